// Round 4
// baseline (296.834 us; speedup 1.0000x reference)
//
#include <hip/hip_runtime.h>
#include <hip/hip_bf16.h>
#include <math.h>

#define B_ 4
#define T_ 2048
#define C_ 1024
#define H_ 16
#define D_ 64

typedef __attribute__((ext_vector_type(8))) short bf16x8_t;   // 8 bf16 (4 VGPRs)
typedef __attribute__((ext_vector_type(4))) float f32x4_t;
typedef __attribute__((ext_vector_type(2))) unsigned int uiv2_t;

// q is pre-scaled by 0.125*log2(e) in the QKV epilogue, so scores arrive in
// base-2: p = exp2(s' - SHIFT2). |s|<=~8 => |s'|<=11.6; SHIFT2=32 keeps
// everything finite-positive; normalization cancels the shift exactly.
// The -SHIFT2 bias is folded into the FIRST MFMA of each score chain as the
// C-operand (a loop-invariant constant), so no per-score subtract and no
// per-iter accumulator zero-init is needed.
#define SHIFT2 32.0f

// async global->LDS DMA, 16B/lane; HW dest = wave-uniform lds base + lane*16
#define GLOAD_LDS16(gp, lp)                                                          \
    __builtin_amdgcn_global_load_lds(                                                \
        (const __attribute__((address_space(1))) void*)(gp),                         \
        (__attribute__((address_space(3))) void*)(lp), 16, 0, 0)

// compiler-only ordering (no instruction): per-wave LDS RAW relies on the
// in-order DS pipe (verified correct rounds 6-7)
#define WAVE_ORDER() __builtin_amdgcn_wave_barrier()

__device__ inline short bf16bits(float f) {
    __hip_bfloat16 h = __float2bfloat16(f);
    return *reinterpret_cast<short*>(&h);
}

__device__ inline unsigned int pack2bf(float a, float b) {
    __hip_bfloat162 h = __float22bfloat162_rn(make_float2(a, b));  // v_cvt_pk_bf16_f32
    return *reinterpret_cast<unsigned int*>(&h);
}

// ---------------------------------------------------------------------------
__global__ void xconv_kernel(const float* __restrict__ in,
                             __hip_bfloat16* __restrict__ out, int n4) {
    int i = blockIdx.x * blockDim.x + threadIdx.x;
    if (i < n4) {
        float4 v = *(const float4*)(in + (size_t)i * 4);
        uint2 u;
        u.x = pack2bf(v.x, v.y);
        u.y = pack2bf(v.z, v.w);
        *(uint2*)(out + (size_t)i * 4) = u;
    }
}

// ---------------------------------------------------------------------------
// RoPE tables: tab[token][0..31]=cos, [32..63]=sin  (f32)
// ---------------------------------------------------------------------------
__global__ void rope_tab_kernel(const int* __restrict__ keep,
                                const int* __restrict__ orig,
                                float* __restrict__ tab) {
    int i = blockIdx.x * blockDim.x + threadIdx.x;   // token*32 + d
    int tok = i >> 5, d = i & 31;
    float freq = 0.5f * exp2f((float)d * (6.321928094887362f / 31.0f));
    float ang  = 6.283185307179586f * ((float)keep[tok] / (float)(*orig)) * freq;
    tab[(size_t)tok * 64 + d]      = cosf(ang);
    tab[(size_t)tok * 64 + 32 + d] = sinf(ang);
}

// ---------------------------------------------------------------------------
__global__ void transpose_conv_kernel(const float* __restrict__ in,
                                      __hip_bfloat16* __restrict__ out,
                                      int K, int N) {
    __shared__ float s[32][33];
    const int n0 = blockIdx.x * 32;
    const int k0 = blockIdx.y * 32;
    const int tx = threadIdx.x;
    const int ty = threadIdx.y;
#pragma unroll
    for (int yy = 0; yy < 32; yy += 8)
        s[ty + yy][tx] = in[(size_t)(k0 + ty + yy) * N + n0 + tx];
    __syncthreads();
#pragma unroll
    for (int yy = 0; yy < 32; yy += 8)
        out[(size_t)(n0 + ty + yy) * K + k0 + tx] = __float2bfloat16(s[tx][ty + yy]);
}

// ---------------------------------------------------------------------------
// GEMM 128x128 tile, BK=32, DOUBLE-BUFFERED global_load_lds staging with
// counted vmcnt (T3-minimum pipeline): issue next tile's DMA, wait
// vmcnt(4) (= only the 4 just-issued loads may remain in flight -> current
// tile's loads drained), barrier, compute, lgkmcnt(0)+barrier (WAR; does NOT
// drain the in-flight next-tile DMA). GROUP_M=8 swizzle.
// MODE 0: f32 store. MODE 1: qkv epilogue (q pre-scaled by 0.125*log2e).
// ---------------------------------------------------------------------------
#define GTILE (128 * 32)

template <int MODE>
__global__ __launch_bounds__(256)
void gemm_kernel(const __hip_bfloat16* __restrict__ A,
                 const __hip_bfloat16* __restrict__ BT,
                 const float* __restrict__ bias,
                 float* __restrict__ out,
                 __hip_bfloat16* __restrict__ qbuf,
                 __hip_bfloat16* __restrict__ kbuf,
                 __hip_bfloat16* __restrict__ vtbuf,
                 const float* __restrict__ ropetab,
                 int M, int N, int K) {
    __shared__ __align__(16) __hip_bfloat16 As[2 * GTILE];
    __shared__ __align__(16) __hip_bfloat16 Bs[2 * GTILE];

    const int tid  = threadIdx.x;
    const int lane = tid & 63;
    const int wave = tid >> 6;
    const int wm   = wave >> 1;
    const int wn   = wave & 1;
    const int l15  = lane & 15;
    const int quad = lane >> 4;

    const int nT  = N >> 7;
    const int grp = blockIdx.x / (8 * nT);
    const int rem = blockIdx.x - grp * 8 * nT;
    const int m0  = (grp * 8 + (rem & 7)) * 128;
    const int n0  = (rem >> 3) * 128;

    f32x4_t acc[4][4];
#pragma unroll
    for (int i = 0; i < 4; i++)
#pragma unroll
        for (int j = 0; j < 4; j++) acc[i][j] = (f32x4_t)0.0f;

    const int lrow = lane >> 2;
    const int lcol = (lane & 3) * 8;
    const __hip_bfloat16* gA  = A  + (size_t)(m0 + wave * 16 + lrow) * K + lcol;
    const __hip_bfloat16* gA2 = gA + (size_t)64 * K;
    const __hip_bfloat16* gB  = BT + (size_t)(n0 + wave * 16 + lrow) * K + lcol;
    const __hip_bfloat16* gB2 = gB + (size_t)64 * K;
    const int ldsW = wave * 16 * 32;   // this wave's stage destination (elements)

    // prologue: stage K-tile 0 into buffer 0 (each wave writes its own rows)
    GLOAD_LDS16(gA,  As + ldsW);
    GLOAD_LDS16(gA2, As + ldsW + 64 * 32);
    GLOAD_LDS16(gB,  Bs + ldsW);
    GLOAD_LDS16(gB2, Bs + ldsW + 64 * 32);

    const int NK = K >> 5;
    for (int t = 0; t < NK; ++t) {
        const int off = (t & 1) * GTILE;
        if (t + 1 < NK) {
            const int noff = off ^ GTILE;
            const int kk   = (t + 1) << 5;
            GLOAD_LDS16(gA  + kk, As + noff + ldsW);
            GLOAD_LDS16(gA2 + kk, As + noff + ldsW + 64 * 32);
            GLOAD_LDS16(gB  + kk, Bs + noff + ldsW);
            GLOAD_LDS16(gB2 + kk, Bs + noff + ldsW + 64 * 32);
            // drain everything EXCEPT the 4 just-issued next-tile loads
            asm volatile("s_waitcnt vmcnt(4)" ::: "memory");
        } else {
            asm volatile("s_waitcnt vmcnt(0)" ::: "memory");
        }
        __builtin_amdgcn_s_barrier();            // all waves' cur-tile DMA done
        __builtin_amdgcn_sched_barrier(0);       // pin: no ds_read hoists above

        bf16x8_t af[4], bfv[4];
#pragma unroll
        for (int i = 0; i < 4; i++)
            af[i] = *(const bf16x8_t*)(As + off + (wm * 64 + i * 16 + l15) * 32 + quad * 8);
#pragma unroll
        for (int j = 0; j < 4; j++)
            bfv[j] = *(const bf16x8_t*)(Bs + off + (wn * 64 + j * 16 + l15) * 32 + quad * 8);
#pragma unroll
        for (int i = 0; i < 4; i++)
#pragma unroll
            for (int j = 0; j < 4; j++)
                acc[i][j] = __builtin_amdgcn_mfma_f32_16x16x32_bf16(af[i], bfv[j], acc[i][j], 0, 0, 0);

        __builtin_amdgcn_sched_barrier(0);       // pin: no ds_read sinks below
        asm volatile("s_waitcnt lgkmcnt(0)" ::: "memory");  // my LDS reads done
        __builtin_amdgcn_s_barrier();            // WAR: safe to overwrite buf next iter
    }

    float bv[4];
#pragma unroll
    for (int j = 0; j < 4; j++)
        bv[j] = bias[n0 + wn * 64 + j * 16 + l15];

    if (MODE == 0) {
#pragma unroll
        for (int i = 0; i < 4; i++)
#pragma unroll
            for (int r = 0; r < 4; r++) {
                int row = m0 + wm * 64 + i * 16 + quad * 4 + r;
#pragma unroll
                for (int j = 0; j < 4; j++) {
                    int col = n0 + wn * 64 + j * 16 + l15;
                    out[(size_t)row * N + col] = acc[i][j][r] + bv[j];
                }
            }
    } else {
        const int cb   = n0 + wn * 64;
        const int part = cb >> 10;           // 0=q 1=k 2=v
        const int h    = (cb & 1023) >> 6;
        if (part == 2) {
#pragma unroll
            for (int j = 0; j < 4; j++) {
#pragma unroll
                for (int i = 0; i < 4; i++) {
#pragma unroll
                    for (int r = 0; r < 4; r++) {
                        int row = m0 + wm * 64 + i * 16 + quad * 4 + r;
                        int b = row >> 11;
                        int t = row & 2047;
                        int d = j * 16 + l15;
                        vtbuf[((size_t)((b * H_ + h) * D_ + d)) * T_ + t] =
                            __float2bfloat16(acc[i][j][r] + bv[j]);
                    }
                }
            }
        } else {
            __hip_bfloat16* dst = (part == 0) ? qbuf : kbuf;
            // q: fold 1/sqrt(D) AND log2(e) so attention uses exp2 directly
            const float sc = (part == 0) ? 0.18033688011112042f : 1.0f;
#pragma unroll
            for (int i = 0; i < 4; i++) {
#pragma unroll
                for (int r = 0; r < 4; r++) {
                    int row = m0 + wm * 64 + i * 16 + quad * 4 + r;
                    int b = row >> 11;
                    int t = row & 2047;
                    const float* trow = ropetab + (size_t)row * 64;
                    size_t base = ((size_t)(b * H_ + h) * T_ + t) * D_;
#pragma unroll
                    for (int j = 0; j < 2; j++) {
                        int d = j * 16 + l15;
                        float cs = trow[d];
                        float sn = trow[32 + d];
                        float x1 = acc[i][j][r]     + bv[j];
                        float x2 = acc[i][j + 2][r] + bv[j + 2];
                        dst[base + d]      = __float2bfloat16(sc * (x1 * cs - x2 * sn));
                        dst[base + d + 32] = __float2bfloat16(sc * (x1 * sn + x2 * cs));
                    }
                }
            }
        }
    }
}

// ---------------------------------------------------------------------------
// Flash attention v8: as v7 (counted-vmcnt double-buffered K/V DMA,
// in-register P^T via permlane swaps) PLUS:
//  - the -SHIFT2 softmax bias is the C-operand of the FIRST MFMA of each
//    score chain (loop-invariant constant regs) -> no per-iter accumulator
//    zero-init and no per-score v_sub before exp2 (~64 VALU instrs/iter gone)
//  - s_setprio(1) around the MFMA clusters (T5; waves here drift between
//    VALU (exp2/permlane) and MFMA phases, so priority arbitration pays)
// ---------------------------------------------------------------------------
#define KVTILE (64 * 64)

__global__ __launch_bounds__(256, 4)
void attn_kernel(const __hip_bfloat16* __restrict__ q,
                 const __hip_bfloat16* __restrict__ k,
                 const __hip_bfloat16* __restrict__ vt,
                 __hip_bfloat16* __restrict__ attn_out) {
    // [0..1]*KVTILE: K double-buffer; [2..3]*KVTILE: V double-buffer (32 KB).
    // After the final barrier the front is reused as the per-wave epilogue
    // staging area (4 waves x 32 x 72 bf16 = 18 KB <= 32 KB).
    __shared__ __align__(16) __hip_bfloat16 SMEM[4 * KVTILE];

    const int tid  = threadIdx.x;
    const int lane = tid & 63;
    const int wave = tid >> 6;
    const int l15  = lane & 15;
    const int quad = lane >> 4;
    const int x7   = l15 & 7;

    const int bh = blockIdx.x & 63;          // XCD swizzle
    const int qt = blockIdx.x >> 6;          // 0..15
    const int b  = bh >> 4;
    const int h  = bh & 15;

    const size_t qkbase = (size_t)bh * T_ * D_;
    const size_t vbase  = (size_t)bh * D_ * T_;
    const int    qrow0  = qt * 128 + wave * 32;

    // DMA lane mapping: lane = drow*8 + dchunk; fetch global chunk dchunk^drow
    const int drow   = lane >> 3;        // 0..7
    const int gchunk = (lane & 7) ^ drow;

    const __hip_bfloat16* kg = k + qkbase;
    const __hip_bfloat16* vg = vt + vbase;

    // fragment-read swizzled chunk offsets (elements)
    const int c0 = ((quad)     ^ x7) * 8;
    const int c1 = ((4 + quad) ^ x7) * 8;

    // Q as B-fragment (n=qrow, k=d), direct global (once)
    bf16x8_t qa[2][2];
#pragma unroll
    for (int qf = 0; qf < 2; qf++)
#pragma unroll
        for (int kk = 0; kk < 2; kk++)
            qa[qf][kk] = *(const bf16x8_t*)(q + qkbase +
                          (size_t)(qrow0 + qf * 16 + l15) * D_ + kk * 32 + quad * 8);

    // all-ones A-fragment for MFMA row-sums
    bf16x8_t ones;
#pragma unroll
    for (int i = 0; i < 8; i++) ones[i] = (short)0x3F80;

    // loop-invariant C-operand for the first MFMA of each score chain:
    // folds the -SHIFT2 softmax bias into the matrix pipe for free
    const f32x4_t mbias = (f32x4_t)(-SHIFT2);

    f32x4_t o[2][4];
#pragma unroll
    for (int qf = 0; qf < 2; qf++)
#pragma unroll
        for (int jd = 0; jd < 4; jd++) o[qf][jd] = (f32x4_t)0.0f;
    f32x4_t osum[2];
    osum[0] = (f32x4_t)0.0f;
    osum[1] = (f32x4_t)0.0f;

    // prologue: stage tile 0 into buffer 0 (iter-0 vmcnt+barrier syncs it)
#pragma unroll
    for (int i = 0; i < 2; i++) {
        int r = wave * 16 + i * 8;
        GLOAD_LDS16(kg + (size_t)(r + drow) * D_ + gchunk * 8, SMEM + r * 64);
        GLOAD_LDS16(vg + (size_t)(r + drow) * T_ + gchunk * 8, SMEM + 2 * KVTILE + r * 64);
    }

    for (int kt = 0; kt < T_ / 64; kt++) {
        const int curoff = (kt & 1) * KVTILE;
        const int nxtoff = curoff ^ KVTILE;
        // issue next tile's DMA FIRST; stays in flight across both barriers
        if (kt + 1 < T_ / 64) {
#pragma unroll
            for (int i = 0; i < 2; i++) {
                int r = wave * 16 + i * 8;
                GLOAD_LDS16(kg + (size_t)((kt + 1) * 64 + r + drow) * D_ + gchunk * 8,
                            SMEM + nxtoff + r * 64);
                GLOAD_LDS16(vg + (size_t)(r + drow) * T_ + (kt + 1) * 64 + gchunk * 8,
                            SMEM + 2 * KVTILE + nxtoff + r * 64);
            }
            // drain everything EXCEPT the 4 just-issued next-tile loads
            asm volatile("s_waitcnt vmcnt(4)" ::: "memory");
        } else {
            asm volatile("s_waitcnt vmcnt(0)" ::: "memory");
        }
        __builtin_amdgcn_s_barrier();            // all waves' cur-tile DMA done
        __builtin_amdgcn_sched_barrier(0);       // pin: no ds_read hoists above

        const __hip_bfloat16* KLc = SMEM + curoff;
        const __hip_bfloat16* VLc = SMEM + 2 * KVTILE + curoff;

        // K fragments (swizzled), then S^T = K.Q^T - SHIFT2 (bias via C-in)
        bf16x8_t kf[4][2];
#pragma unroll
        for (int jt = 0; jt < 4; jt++) {
            kf[jt][0] = *(const bf16x8_t*)(KLc + (jt * 16 + l15) * 64 + c0);
            kf[jt][1] = *(const bf16x8_t*)(KLc + (jt * 16 + l15) * 64 + c1);
        }

        f32x4_t sT[2][4];
        __builtin_amdgcn_s_setprio(1);
#pragma unroll
        for (int jt = 0; jt < 4; jt++)
#pragma unroll
            for (int qf = 0; qf < 2; qf++) {
                sT[qf][jt] = __builtin_amdgcn_mfma_f32_16x16x32_bf16(
                    kf[jt][0], qa[qf][0], mbias, 0, 0, 0);
                sT[qf][jt] = __builtin_amdgcn_mfma_f32_16x16x32_bf16(
                    kf[jt][1], qa[qf][1], sT[qf][jt], 0, 0, 0);
            }
        __builtin_amdgcn_s_setprio(0);

        // p = exp2(s'); pack to bf16 pairs, then build P^T B-fragments
        // entirely in registers via permlane swaps (no LDS round-trip).
        bf16x8_t pb[2][2];
#pragma unroll
        for (int qf = 0; qf < 2; qf++) {
            unsigned int w0[4], w1[4];
#pragma unroll
            for (int jt = 0; jt < 4; jt++) {
                float p0 = __builtin_amdgcn_exp2f(sT[qf][jt][0]);
                float p1 = __builtin_amdgcn_exp2f(sT[qf][jt][1]);
                float p2 = __builtin_amdgcn_exp2f(sT[qf][jt][2]);
                float p3 = __builtin_amdgcn_exp2f(sT[qf][jt][3]);
                w0[jt] = pack2bf(p0, p1);   // keys quad*4+0, +1
                w1[jt] = pack2bf(p2, p3);   // keys quad*4+2, +3
            }
#pragma unroll
            for (int kk = 0; kk < 2; kk++) {
                uiv2_t s0 = __builtin_amdgcn_permlane32_swap(w0[2 * kk], w0[2 * kk + 1], false, false);
                uiv2_t r0 = __builtin_amdgcn_permlane16_swap(s0[0], s0[1], false, false);
                uiv2_t s1 = __builtin_amdgcn_permlane32_swap(w1[2 * kk], w1[2 * kk + 1], false, false);
                uiv2_t r1 = __builtin_amdgcn_permlane16_swap(s1[0], s1[1], false, false);
                union { unsigned int u[4]; bf16x8_t v; } pu;
                pu.u[0] = r0[0];   // keys +0,1
                pu.u[1] = r1[0];   // keys +2,3
                pu.u[2] = r0[1];   // keys +4,5
                pu.u[3] = r1[1];   // keys +6,7
                pb[qf][kk] = pu.v;
            }
        }

        __builtin_amdgcn_s_setprio(1);
        // row-sums via ones-MFMA: every D row = sum_k P[n][k]
#pragma unroll
        for (int qf = 0; qf < 2; qf++) {
            osum[qf] = __builtin_amdgcn_mfma_f32_16x16x32_bf16(ones, pb[qf][0], osum[qf], 0, 0, 0);
            osum[qf] = __builtin_amdgcn_mfma_f32_16x16x32_bf16(ones, pb[qf][1], osum[qf], 0, 0, 0);
        }

        // o^T += V^T.P^T
#pragma unroll
        for (int jd = 0; jd < 4; jd++) {
            bf16x8_t vf0 = *(const bf16x8_t*)(VLc + (jd * 16 + l15) * 64 + c0);
            bf16x8_t vf1 = *(const bf16x8_t*)(VLc + (jd * 16 + l15) * 64 + c1);
#pragma unroll
            for (int qf = 0; qf < 2; qf++) {
                o[qf][jd] = __builtin_amdgcn_mfma_f32_16x16x32_bf16(vf0, pb[qf][0], o[qf][jd], 0, 0, 0);
                o[qf][jd] = __builtin_amdgcn_mfma_f32_16x16x32_bf16(vf1, pb[qf][1], o[qf][jd], 0, 0, 0);
            }
        }
        __builtin_amdgcn_s_setprio(0);

        __builtin_amdgcn_sched_barrier(0);       // pin: no ds_read sinks below
        asm volatile("s_waitcnt lgkmcnt(0)" ::: "memory");  // my LDS reads done
        __builtin_amdgcn_s_barrier();            // WAR: next iter may overwrite
    }

    // per-qrow inverse sums (all lanes/quads hold the value for their l15)
    float inv[2];
    inv[0] = 1.0f / osum[0][0];
    inv[1] = 1.0f / osum[1][0];

    // epilogue staging: reuse SMEM front (all K/V reads are behind the final
    // barrier above); per-wave private [32][72] bf16 region
    __hip_bfloat16* Pep = SMEM + wave * (32 * 72);

    WAVE_ORDER();
    // o^T -> LDS (packed b64), then coalesced 16B store
#pragma unroll
    for (int qf = 0; qf < 2; qf++) {
#pragma unroll
        for (int jd = 0; jd < 4; jd++) {
            uint2 pk;
            pk.x = pack2bf(o[qf][jd][0] * inv[qf], o[qf][jd][1] * inv[qf]);
            pk.y = pack2bf(o[qf][jd][2] * inv[qf], o[qf][jd][3] * inv[qf]);
            *(uint2*)(Pep + (qf * 16 + l15) * 72 + jd * 16 + quad * 4) = pk;
        }
    }
    WAVE_ORDER();

#pragma unroll
    for (int rnd = 0; rnd < 4; rnd++) {
        int row = rnd * 8 + (lane >> 3);
        int col = (lane & 7) * 8;
        bf16x8_t vrow = *(const bf16x8_t*)(Pep + row * 72 + col);
        int token = qt * 128 + wave * 32 + row;
        *(bf16x8_t*)(attn_out + ((size_t)(b * T_ + token)) * C_ + h * 64 + col) = vrow;
    }
}

// ---------------------------------------------------------------------------
extern "C" void kernel_launch(void* const* d_in, const int* in_sizes, int n_in,
                              void* d_out, int out_size, void* d_ws, size_t ws_size,
                              hipStream_t stream) {
    const float* x        = (const float*)d_in[0];
    const int*   keep_idx = (const int*)d_in[1];
    const int*   orig_len = (const int*)d_in[2];
    const float* Wqkv     = (const float*)d_in[3];
    const float* bqkv     = (const float*)d_in[4];
    const float* Wproj    = (const float*)d_in[5];
    const float* bproj    = (const float*)d_in[6];
    float*       out      = (float*)d_out;

    const size_t NTOK = (size_t)B_ * T_;
    const size_t QKV1 = NTOK * C_;

    __hip_bfloat16* qbuf    = (__hip_bfloat16*)d_ws;
    __hip_bfloat16* kbuf    = qbuf    + QKV1;
    __hip_bfloat16* vtbuf   = kbuf    + QKV1;
    __hip_bfloat16* attnbuf = vtbuf   + QKV1;
    __hip_bfloat16* WqkvT   = attnbuf + QKV1;
    __hip_bfloat16* WprojT  = WqkvT   + (size_t)C_ * 3 * C_;
    __hip_bfloat16* xbf     = WprojT  + (size_t)C_ * C_;
    float*          ropetab = (float*)(xbf + QKV1);

    xconv_kernel<<<(QKV1 / 4 + 255) / 256, 256, 0, stream>>>(x, xbf, (int)(QKV1 / 4));
    rope_tab_kernel<<<(NTOK * 32) / 256, 256, 0, stream>>>(keep_idx, orig_len, ropetab);

    dim3 tb(32, 8);
    transpose_conv_kernel<<<dim3(3 * C_ / 32, C_ / 32), tb, 0, stream>>>(Wqkv, WqkvT, C_, 3 * C_);
    transpose_conv_kernel<<<dim3(C_ / 32, C_ / 32), tb, 0, stream>>>(Wproj, WprojT, C_, C_);

    gemm_kernel<1><<<(8192 / 128) * (3072 / 128), 256, 0, stream>>>(
        xbf, WqkvT, bqkv, nullptr, qbuf, kbuf, vtbuf, ropetab, 8192, 3072, 1024);

    attn_kernel<<<(T_ / 128) * 64, 256, 0, stream>>>(qbuf, kbuf, vtbuf, attnbuf);

    gemm_kernel<0><<<(8192 / 128) * (1024 / 128), 256, 0, stream>>>(
        attnbuf, WprojT, bproj, out, nullptr, nullptr, nullptr, nullptr, 8192, 1024, 1024);
}

// Round 5
// 269.862 us; speedup vs baseline: 1.1000x; 1.1000x over previous
//
#include <hip/hip_runtime.h>
#include <hip/hip_bf16.h>
#include <math.h>

#define B_ 4
#define T_ 2048
#define C_ 1024
#define H_ 16
#define D_ 64

typedef __attribute__((ext_vector_type(8))) short bf16x8_t;   // 8 bf16 (4 VGPRs)
typedef __attribute__((ext_vector_type(4))) float f32x4_t;
typedef __attribute__((ext_vector_type(2))) unsigned int uiv2_t;

// q is pre-scaled by 0.125*log2(e) in the QKV epilogue, so scores arrive in
// base-2: p = exp2(s' - SHIFT2). |s|<=~8 => |s'|<=11.6; SHIFT2=32 keeps
// everything finite-positive; normalization cancels the shift exactly.
// The -SHIFT2 bias rides in as the C-operand of the first MFMA of each chain.
#define SHIFT2 32.0f

// async global->LDS DMA, 16B/lane; HW dest = wave-uniform lds base + lane*16
#define GLOAD_LDS16(gp, lp)                                                          \
    __builtin_amdgcn_global_load_lds(                                                \
        (const __attribute__((address_space(1))) void*)(gp),                         \
        (__attribute__((address_space(3))) void*)(lp), 16, 0, 0)

// compiler-only ordering (no instruction): per-wave LDS RAW relies on the
// in-order DS pipe (verified correct rounds 6-7)
#define WAVE_ORDER() __builtin_amdgcn_wave_barrier()

__device__ inline short bf16bits(float f) {
    __hip_bfloat16 h = __float2bfloat16(f);
    return *reinterpret_cast<short*>(&h);
}

__device__ inline unsigned int pack2bf(float a, float b) {
    __hip_bfloat162 h = __float22bfloat162_rn(make_float2(a, b));  // v_cvt_pk_bf16_f32
    return *reinterpret_cast<unsigned int*>(&h);
}

// ---------------------------------------------------------------------------
__global__ void xconv_kernel(const float* __restrict__ in,
                             __hip_bfloat16* __restrict__ out, int n4) {
    int i = blockIdx.x * blockDim.x + threadIdx.x;
    if (i < n4) {
        float4 v = *(const float4*)(in + (size_t)i * 4);
        uint2 u;
        u.x = pack2bf(v.x, v.y);
        u.y = pack2bf(v.z, v.w);
        *(uint2*)(out + (size_t)i * 4) = u;
    }
}

// ---------------------------------------------------------------------------
// RoPE tables: tab[token][0..31]=cos, [32..63]=sin  (f32)
// ---------------------------------------------------------------------------
__global__ void rope_tab_kernel(const int* __restrict__ keep,
                                const int* __restrict__ orig,
                                float* __restrict__ tab) {
    int i = blockIdx.x * blockDim.x + threadIdx.x;   // token*32 + d
    int tok = i >> 5, d = i & 31;
    float freq = 0.5f * exp2f((float)d * (6.321928094887362f / 31.0f));
    float ang  = 6.283185307179586f * ((float)keep[tok] / (float)(*orig)) * freq;
    tab[(size_t)tok * 64 + d]      = cosf(ang);
    tab[(size_t)tok * 64 + 32 + d] = sinf(ang);
}

// ---------------------------------------------------------------------------
__global__ void transpose_conv_kernel(const float* __restrict__ in,
                                      __hip_bfloat16* __restrict__ out,
                                      int K, int N) {
    __shared__ float s[32][33];
    const int n0 = blockIdx.x * 32;
    const int k0 = blockIdx.y * 32;
    const int tx = threadIdx.x;
    const int ty = threadIdx.y;
#pragma unroll
    for (int yy = 0; yy < 32; yy += 8)
        s[ty + yy][tx] = in[(size_t)(k0 + ty + yy) * N + n0 + tx];
    __syncthreads();
#pragma unroll
    for (int yy = 0; yy < 32; yy += 8)
        out[(size_t)(n0 + ty + yy) * K + k0 + tx] = __float2bfloat16(s[tx][ty + yy]);
}

// ---------------------------------------------------------------------------
// GEMM 128x128 tile, BK=32, TRIPLE-BUFFERED global_load_lds staging with
// 2-deep counted-vmcnt pipeline: at iter t issue tile t+2's DMA, then wait
// vmcnt(8) (= tiles t+1,t+2 may stay in flight -> tile t drained; the wait
// targets loads issued TWO iterations ago, covering ~900cy HBM latency).
// LDS XOR swizzle (T2, both-sides): staging lane loads pre-swizzled global
// chunk (l&3)^((l>>4)&3) into a LINEAR LDS dest; fragment reads use chunk
// quad^(l15>>2). Banks per read: 8 banks x 2 lanes = 2-way (free) vs the
// 8-way of the unswizzled layout (row stride 64B -> banks {0,16} only).
// MODE 0: f32 store. MODE 1: qkv epilogue; V is transposed through LDS
// (free after the K-loop) for coalesced 16B vtbuf stores.
// ---------------------------------------------------------------------------
#define GTILE (128 * 32)

template <int MODE>
__global__ __launch_bounds__(256)
void gemm_kernel(const __hip_bfloat16* __restrict__ A,
                 const __hip_bfloat16* __restrict__ BT,
                 const float* __restrict__ bias,
                 float* __restrict__ out,
                 __hip_bfloat16* __restrict__ qbuf,
                 __hip_bfloat16* __restrict__ kbuf,
                 __hip_bfloat16* __restrict__ vtbuf,
                 const float* __restrict__ ropetab,
                 int M, int N, int K) {
    // GS[0..3*GTILE): A triple-buffer; GS[3*GTILE..6*GTILE): B triple-buffer.
    __shared__ __align__(16) __hip_bfloat16 GS[6 * GTILE];

    const int tid  = threadIdx.x;
    const int lane = tid & 63;
    const int wave = tid >> 6;
    const int wm   = wave >> 1;
    const int wn   = wave & 1;
    const int l15  = lane & 15;
    const int quad = lane >> 4;

    const int nT  = N >> 7;
    const int grp = blockIdx.x / (8 * nT);
    const int rem = blockIdx.x - grp * 8 * nT;
    const int m0  = (grp * 8 + (rem & 7)) * 128;
    const int n0  = (rem >> 3) * 128;

    f32x4_t acc[4][4];
#pragma unroll
    for (int i = 0; i < 4; i++)
#pragma unroll
        for (int j = 0; j < 4; j++) acc[i][j] = (f32x4_t)0.0f;

    const int lrow = lane >> 2;
    // pre-swizzled source chunk: LDS[row][p] holds global chunk p^((row>>2)&3)
    const int scol = ((lane & 3) ^ ((lane >> 4) & 3)) * 8;
    const __hip_bfloat16* gA  = A  + (size_t)(m0 + wave * 16 + lrow) * K + scol;
    const __hip_bfloat16* gA2 = gA + (size_t)64 * K;
    const __hip_bfloat16* gB  = BT + (size_t)(n0 + wave * 16 + lrow) * K + scol;
    const __hip_bfloat16* gB2 = gB + (size_t)64 * K;
    const int ldsW = wave * 16 * 32;   // this wave's stage destination (elements)

    const int NK = K >> 5;
    // prologue: stage K-tiles 0 and 1 into buffers 0 and 1
    GLOAD_LDS16(gA,  GS + ldsW);
    GLOAD_LDS16(gA2, GS + ldsW + 64 * 32);
    GLOAD_LDS16(gB,  GS + 3 * GTILE + ldsW);
    GLOAD_LDS16(gB2, GS + 3 * GTILE + ldsW + 64 * 32);
    if (NK > 1) {
        GLOAD_LDS16(gA  + 32, GS + GTILE + ldsW);
        GLOAD_LDS16(gA2 + 32, GS + GTILE + ldsW + 64 * 32);
        GLOAD_LDS16(gB  + 32, GS + 3 * GTILE + GTILE + ldsW);
        GLOAD_LDS16(gB2 + 32, GS + 3 * GTILE + GTILE + ldsW + 64 * 32);
    }

    int off = 0;
    for (int t = 0; t < NK; ++t) {
        if (t + 2 < NK) {
            int poff = off + 2 * GTILE;
            if (poff >= 3 * GTILE) poff -= 3 * GTILE;
            const int kk = (t + 2) << 5;
            GLOAD_LDS16(gA  + kk, GS + poff + ldsW);
            GLOAD_LDS16(gA2 + kk, GS + poff + ldsW + 64 * 32);
            GLOAD_LDS16(gB  + kk, GS + 3 * GTILE + poff + ldsW);
            GLOAD_LDS16(gB2 + kk, GS + 3 * GTILE + poff + ldsW + 64 * 32);
            // leave only tiles t+1,t+2 (8 newest) in flight; tile t drained
            asm volatile("s_waitcnt vmcnt(8)" ::: "memory");
        } else if (t + 1 < NK) {
            asm volatile("s_waitcnt vmcnt(4)" ::: "memory");
        } else {
            asm volatile("s_waitcnt vmcnt(0)" ::: "memory");
        }
        __builtin_amdgcn_s_barrier();            // all waves' cur-tile DMA done
        __builtin_amdgcn_sched_barrier(0);       // pin: no ds_read hoists above

        bf16x8_t af[4], bfv[4];
#pragma unroll
        for (int i = 0; i < 4; i++)
            af[i] = *(const bf16x8_t*)(GS + off + (wm * 64 + i * 16 + l15) * 32 +
                                       ((quad ^ (l15 >> 2)) * 8));
#pragma unroll
        for (int j = 0; j < 4; j++)
            bfv[j] = *(const bf16x8_t*)(GS + 3 * GTILE + off + (wn * 64 + j * 16 + l15) * 32 +
                                        ((quad ^ (l15 >> 2)) * 8));
#pragma unroll
        for (int i = 0; i < 4; i++)
#pragma unroll
            for (int j = 0; j < 4; j++)
                acc[i][j] = __builtin_amdgcn_mfma_f32_16x16x32_bf16(af[i], bfv[j], acc[i][j], 0, 0, 0);

        __builtin_amdgcn_sched_barrier(0);       // pin: no ds_read sinks below
        asm volatile("s_waitcnt lgkmcnt(0)" ::: "memory");  // my LDS reads done
        __builtin_amdgcn_s_barrier();            // WAR: buffer reusable

        off += GTILE;
        if (off == 3 * GTILE) off = 0;
    }

    float bv[4];
#pragma unroll
    for (int j = 0; j < 4; j++)
        bv[j] = bias[n0 + wn * 64 + j * 16 + l15];

    if (MODE == 0) {
#pragma unroll
        for (int i = 0; i < 4; i++)
#pragma unroll
            for (int r = 0; r < 4; r++) {
                int row = m0 + wm * 64 + i * 16 + quad * 4 + r;
#pragma unroll
                for (int j = 0; j < 4; j++) {
                    int col = n0 + wn * 64 + j * 16 + l15;
                    out[(size_t)row * N + col] = acc[i][j][r] + bv[j];
                }
            }
    } else {
        const int cb   = n0 + wn * 64;
        const int part = cb >> 10;           // 0=q 1=k 2=v  (uniform per block)
        if (part == 2) {
            // transpose 128t x 128d(2 heads) through LDS (free after K-loop),
            // then coalesced 16B stores. Region per wn: 64 d-rows x 136 (pad).
            const int hb = (n0 & 1023) >> 6;     // head at wn=0; wn adds +1
            __hip_bfloat16* myL = GS + wn * (64 * 136);
#pragma unroll
            for (int j = 0; j < 4; j++)
#pragma unroll
                for (int i = 0; i < 4; i++)
#pragma unroll
                    for (int r = 0; r < 4; r++) {
                        int rt = wm * 64 + i * 16 + quad * 4 + r;   // token in tile
                        int d  = j * 16 + l15;
                        myL[d * 136 + rt] = __float2bfloat16(acc[i][j][r] + bv[j]);
                    }
            __syncthreads();
            const int bb  = m0 >> 11;
            const int t0  = m0 & 2047;
            const int row = tid >> 1;            // 0..127 = wn2*64 + d
            const int wn2 = row >> 6;
            const int dd  = row & 63;
            const __hip_bfloat16* src = GS + wn2 * (64 * 136) + dd * 136;
            __hip_bfloat16* dstv = vtbuf +
                ((size_t)((bb * H_ + hb + wn2) * D_ + dd)) * T_ + t0;
#pragma unroll
            for (int s = 0; s < 8; s++) {
                int ch = (tid & 1) * 8 + s;
                *(bf16x8_t*)(dstv + ch * 8) = *(const bf16x8_t*)(src + ch * 8);
            }
        } else {
            const int h = (cb & 1023) >> 6;
            __hip_bfloat16* dst = (part == 0) ? qbuf : kbuf;
            // q: fold 1/sqrt(D) AND log2(e) so attention uses exp2 directly
            const float sc = (part == 0) ? 0.18033688011112042f : 1.0f;
#pragma unroll
            for (int i = 0; i < 4; i++) {
#pragma unroll
                for (int r = 0; r < 4; r++) {
                    int row = m0 + wm * 64 + i * 16 + quad * 4 + r;
                    int b = row >> 11;
                    int t = row & 2047;
                    const float* trow = ropetab + (size_t)row * 64;
                    size_t base = ((size_t)(b * H_ + h) * T_ + t) * D_;
#pragma unroll
                    for (int j = 0; j < 2; j++) {
                        int d = j * 16 + l15;
                        float cs = trow[d];
                        float sn = trow[32 + d];
                        float x1 = acc[i][j][r]     + bv[j];
                        float x2 = acc[i][j + 2][r] + bv[j + 2];
                        dst[base + d]      = __float2bfloat16(sc * (x1 * cs - x2 * sn));
                        dst[base + d + 32] = __float2bfloat16(sc * (x1 * sn + x2 * cs));
                    }
                }
            }
        }
    }
}

// ---------------------------------------------------------------------------
// Flash attention v8: counted-vmcnt double-buffered K/V DMA, in-register P^T
// via permlane swaps, -SHIFT2 folded into MFMA C-in, setprio around MFMA.
// ---------------------------------------------------------------------------
#define KVTILE (64 * 64)

__global__ __launch_bounds__(256, 4)
void attn_kernel(const __hip_bfloat16* __restrict__ q,
                 const __hip_bfloat16* __restrict__ k,
                 const __hip_bfloat16* __restrict__ vt,
                 __hip_bfloat16* __restrict__ attn_out) {
    // [0..1]*KVTILE: K double-buffer; [2..3]*KVTILE: V double-buffer (32 KB).
    // After the final barrier the front is reused as the per-wave epilogue
    // staging area (4 waves x 32 x 72 bf16 = 18 KB <= 32 KB).
    __shared__ __align__(16) __hip_bfloat16 SMEM[4 * KVTILE];

    const int tid  = threadIdx.x;
    const int lane = tid & 63;
    const int wave = tid >> 6;
    const int l15  = lane & 15;
    const int quad = lane >> 4;
    const int x7   = l15 & 7;

    const int bh = blockIdx.x & 63;          // XCD swizzle
    const int qt = blockIdx.x >> 6;          // 0..15
    const int b  = bh >> 4;
    const int h  = bh & 15;

    const size_t qkbase = (size_t)bh * T_ * D_;
    const size_t vbase  = (size_t)bh * D_ * T_;
    const int    qrow0  = qt * 128 + wave * 32;

    // DMA lane mapping: lane = drow*8 + dchunk; fetch global chunk dchunk^drow
    const int drow   = lane >> 3;        // 0..7
    const int gchunk = (lane & 7) ^ drow;

    const __hip_bfloat16* kg = k + qkbase;
    const __hip_bfloat16* vg = vt + vbase;

    // fragment-read swizzled chunk offsets (elements)
    const int c0 = ((quad)     ^ x7) * 8;
    const int c1 = ((4 + quad) ^ x7) * 8;

    // Q as B-fragment (n=qrow, k=d), direct global (once)
    bf16x8_t qa[2][2];
#pragma unroll
    for (int qf = 0; qf < 2; qf++)
#pragma unroll
        for (int kk = 0; kk < 2; kk++)
            qa[qf][kk] = *(const bf16x8_t*)(q + qkbase +
                          (size_t)(qrow0 + qf * 16 + l15) * D_ + kk * 32 + quad * 8);

    // all-ones A-fragment for MFMA row-sums
    bf16x8_t ones;
#pragma unroll
    for (int i = 0; i < 8; i++) ones[i] = (short)0x3F80;

    // loop-invariant C-operand: folds the -SHIFT2 softmax bias into the MFMA
    const f32x4_t mbias = (f32x4_t)(-SHIFT2);

    f32x4_t o[2][4];
#pragma unroll
    for (int qf = 0; qf < 2; qf++)
#pragma unroll
        for (int jd = 0; jd < 4; jd++) o[qf][jd] = (f32x4_t)0.0f;
    f32x4_t osum[2];
    osum[0] = (f32x4_t)0.0f;
    osum[1] = (f32x4_t)0.0f;

    // prologue: stage tile 0 into buffer 0 (iter-0 vmcnt+barrier syncs it)
#pragma unroll
    for (int i = 0; i < 2; i++) {
        int r = wave * 16 + i * 8;
        GLOAD_LDS16(kg + (size_t)(r + drow) * D_ + gchunk * 8, SMEM + r * 64);
        GLOAD_LDS16(vg + (size_t)(r + drow) * T_ + gchunk * 8, SMEM + 2 * KVTILE + r * 64);
    }

    for (int kt = 0; kt < T_ / 64; kt++) {
        const int curoff = (kt & 1) * KVTILE;
        const int nxtoff = curoff ^ KVTILE;
        // issue next tile's DMA FIRST; stays in flight across both barriers
        if (kt + 1 < T_ / 64) {
#pragma unroll
            for (int i = 0; i < 2; i++) {
                int r = wave * 16 + i * 8;
                GLOAD_LDS16(kg + (size_t)((kt + 1) * 64 + r + drow) * D_ + gchunk * 8,
                            SMEM + nxtoff + r * 64);
                GLOAD_LDS16(vg + (size_t)(r + drow) * T_ + (kt + 1) * 64 + gchunk * 8,
                            SMEM + 2 * KVTILE + nxtoff + r * 64);
            }
            // drain everything EXCEPT the 4 just-issued next-tile loads
            asm volatile("s_waitcnt vmcnt(4)" ::: "memory");
        } else {
            asm volatile("s_waitcnt vmcnt(0)" ::: "memory");
        }
        __builtin_amdgcn_s_barrier();            // all waves' cur-tile DMA done
        __builtin_amdgcn_sched_barrier(0);       // pin: no ds_read hoists above

        const __hip_bfloat16* KLc = SMEM + curoff;
        const __hip_bfloat16* VLc = SMEM + 2 * KVTILE + curoff;

        // K fragments (swizzled), then S^T = K.Q^T - SHIFT2 (bias via C-in)
        bf16x8_t kf[4][2];
#pragma unroll
        for (int jt = 0; jt < 4; jt++) {
            kf[jt][0] = *(const bf16x8_t*)(KLc + (jt * 16 + l15) * 64 + c0);
            kf[jt][1] = *(const bf16x8_t*)(KLc + (jt * 16 + l15) * 64 + c1);
        }

        f32x4_t sT[2][4];
        __builtin_amdgcn_s_setprio(1);
#pragma unroll
        for (int jt = 0; jt < 4; jt++)
#pragma unroll
            for (int qf = 0; qf < 2; qf++) {
                sT[qf][jt] = __builtin_amdgcn_mfma_f32_16x16x32_bf16(
                    kf[jt][0], qa[qf][0], mbias, 0, 0, 0);
                sT[qf][jt] = __builtin_amdgcn_mfma_f32_16x16x32_bf16(
                    kf[jt][1], qa[qf][1], sT[qf][jt], 0, 0, 0);
            }
        __builtin_amdgcn_s_setprio(0);

        // p = exp2(s'); pack to bf16 pairs, then build P^T B-fragments
        // entirely in registers via permlane swaps (no LDS round-trip).
        bf16x8_t pb[2][2];
#pragma unroll
        for (int qf = 0; qf < 2; qf++) {
            unsigned int w0[4], w1[4];
#pragma unroll
            for (int jt = 0; jt < 4; jt++) {
                float p0 = __builtin_amdgcn_exp2f(sT[qf][jt][0]);
                float p1 = __builtin_amdgcn_exp2f(sT[qf][jt][1]);
                float p2 = __builtin_amdgcn_exp2f(sT[qf][jt][2]);
                float p3 = __builtin_amdgcn_exp2f(sT[qf][jt][3]);
                w0[jt] = pack2bf(p0, p1);   // keys quad*4+0, +1
                w1[jt] = pack2bf(p2, p3);   // keys quad*4+2, +3
            }
#pragma unroll
            for (int kk = 0; kk < 2; kk++) {
                uiv2_t s0 = __builtin_amdgcn_permlane32_swap(w0[2 * kk], w0[2 * kk + 1], false, false);
                uiv2_t r0 = __builtin_amdgcn_permlane16_swap(s0[0], s0[1], false, false);
                uiv2_t s1 = __builtin_amdgcn_permlane32_swap(w1[2 * kk], w1[2 * kk + 1], false, false);
                uiv2_t r1 = __builtin_amdgcn_permlane16_swap(s1[0], s1[1], false, false);
                union { unsigned int u[4]; bf16x8_t v; } pu;
                pu.u[0] = r0[0];   // keys +0,1
                pu.u[1] = r1[0];   // keys +2,3
                pu.u[2] = r0[1];   // keys +4,5
                pu.u[3] = r1[1];   // keys +6,7
                pb[qf][kk] = pu.v;
            }
        }

        __builtin_amdgcn_s_setprio(1);
        // row-sums via ones-MFMA: every D row = sum_k P[n][k]
#pragma unroll
        for (int qf = 0; qf < 2; qf++) {
            osum[qf] = __builtin_amdgcn_mfma_f32_16x16x32_bf16(ones, pb[qf][0], osum[qf], 0, 0, 0);
            osum[qf] = __builtin_amdgcn_mfma_f32_16x16x32_bf16(ones, pb[qf][1], osum[qf], 0, 0, 0);
        }

        // o^T += V^T.P^T
#pragma unroll
        for (int jd = 0; jd < 4; jd++) {
            bf16x8_t vf0 = *(const bf16x8_t*)(VLc + (jd * 16 + l15) * 64 + c0);
            bf16x8_t vf1 = *(const bf16x8_t*)(VLc + (jd * 16 + l15) * 64 + c1);
#pragma unroll
            for (int qf = 0; qf < 2; qf++) {
                o[qf][jd] = __builtin_amdgcn_mfma_f32_16x16x32_bf16(vf0, pb[qf][0], o[qf][jd], 0, 0, 0);
                o[qf][jd] = __builtin_amdgcn_mfma_f32_16x16x32_bf16(vf1, pb[qf][1], o[qf][jd], 0, 0, 0);
            }
        }
        __builtin_amdgcn_s_setprio(0);

        __builtin_amdgcn_sched_barrier(0);       // pin: no ds_read sinks below
        asm volatile("s_waitcnt lgkmcnt(0)" ::: "memory");  // my LDS reads done
        __builtin_amdgcn_s_barrier();            // WAR: next iter may overwrite
    }

    // per-qrow inverse sums (all lanes/quads hold the value for their l15)
    float inv[2];
    inv[0] = 1.0f / osum[0][0];
    inv[1] = 1.0f / osum[1][0];

    // epilogue staging: reuse SMEM front (all K/V reads are behind the final
    // barrier above); per-wave private [32][72] bf16 region
    __hip_bfloat16* Pep = SMEM + wave * (32 * 72);

    WAVE_ORDER();
    // o^T -> LDS (packed b64), then coalesced 16B store
#pragma unroll
    for (int qf = 0; qf < 2; qf++) {
#pragma unroll
        for (int jd = 0; jd < 4; jd++) {
            uint2 pk;
            pk.x = pack2bf(o[qf][jd][0] * inv[qf], o[qf][jd][1] * inv[qf]);
            pk.y = pack2bf(o[qf][jd][2] * inv[qf], o[qf][jd][3] * inv[qf]);
            *(uint2*)(Pep + (qf * 16 + l15) * 72 + jd * 16 + quad * 4) = pk;
        }
    }
    WAVE_ORDER();

#pragma unroll
    for (int rnd = 0; rnd < 4; rnd++) {
        int row = rnd * 8 + (lane >> 3);
        int col = (lane & 7) * 8;
        bf16x8_t vrow = *(const bf16x8_t*)(Pep + row * 72 + col);
        int token = qt * 128 + wave * 32 + row;
        *(bf16x8_t*)(attn_out + ((size_t)(b * T_ + token)) * C_ + h * 64 + col) = vrow;
    }
}

// ---------------------------------------------------------------------------
extern "C" void kernel_launch(void* const* d_in, const int* in_sizes, int n_in,
                              void* d_out, int out_size, void* d_ws, size_t ws_size,
                              hipStream_t stream) {
    const float* x        = (const float*)d_in[0];
    const int*   keep_idx = (const int*)d_in[1];
    const int*   orig_len = (const int*)d_in[2];
    const float* Wqkv     = (const float*)d_in[3];
    const float* bqkv     = (const float*)d_in[4];
    const float* Wproj    = (const float*)d_in[5];
    const float* bproj    = (const float*)d_in[6];
    float*       out      = (float*)d_out;

    const size_t NTOK = (size_t)B_ * T_;
    const size_t QKV1 = NTOK * C_;

    __hip_bfloat16* qbuf    = (__hip_bfloat16*)d_ws;
    __hip_bfloat16* kbuf    = qbuf    + QKV1;
    __hip_bfloat16* vtbuf   = kbuf    + QKV1;
    __hip_bfloat16* attnbuf = vtbuf   + QKV1;
    __hip_bfloat16* WqkvT   = attnbuf + QKV1;
    __hip_bfloat16* WprojT  = WqkvT   + (size_t)C_ * 3 * C_;
    __hip_bfloat16* xbf     = WprojT  + (size_t)C_ * C_;
    float*          ropetab = (float*)(xbf + QKV1);

    xconv_kernel<<<(QKV1 / 4 + 255) / 256, 256, 0, stream>>>(x, xbf, (int)(QKV1 / 4));
    rope_tab_kernel<<<(NTOK * 32) / 256, 256, 0, stream>>>(keep_idx, orig_len, ropetab);

    dim3 tb(32, 8);
    transpose_conv_kernel<<<dim3(3 * C_ / 32, C_ / 32), tb, 0, stream>>>(Wqkv, WqkvT, C_, 3 * C_);
    transpose_conv_kernel<<<dim3(C_ / 32, C_ / 32), tb, 0, stream>>>(Wproj, WprojT, C_, C_);

    gemm_kernel<1><<<(8192 / 128) * (3072 / 128), 256, 0, stream>>>(
        xbf, WqkvT, bqkv, nullptr, qbuf, kbuf, vtbuf, ropetab, 8192, 3072, 1024);

    attn_kernel<<<(T_ / 128) * 64, 256, 0, stream>>>(qbuf, kbuf, vtbuf, attnbuf);

    gemm_kernel<0><<<(8192 / 128) * (1024 / 128), 256, 0, stream>>>(
        attnbuf, WprojT, bproj, out, nullptr, nullptr, nullptr, nullptr, 8192, 1024, 1024);
}